// Round 4
// baseline (1319.236 us; speedup 1.0000x reference)
//
#include <hip/hip_runtime.h>
#include <math.h>

#define N_NODES 100000
#define N_EDGES 3200000
#define NF 256

typedef unsigned short u16;
typedef unsigned int u32;

typedef __bf16 bf16x8_t __attribute__((ext_vector_type(8)));
typedef float f32x4_t __attribute__((ext_vector_type(4)));

__device__ __forceinline__ float bf2f(u16 u) {
  union { u32 i; float f; } v; v.i = ((u32)u) << 16; return v.f;
}
__device__ __forceinline__ u16 f2bf(float f) {
  union { float f; u32 i; } v; v.f = f;
  u32 x = v.i;
  u32 r = (x + 0x7FFFu + ((x >> 16) & 1u)) >> 16;
  return (u16)r;
}

// ---- dtype sniff: bf16-NaN bit patterns appear in f32 mantissa halves only ----
__global__ void sniff_kernel(const u16* __restrict__ xr, int* __restrict__ flag) {
  __shared__ int cnt;
  if (threadIdx.x == 0) cnt = 0;
  __syncthreads();
  int c = 0;
  for (int i = threadIdx.x; i < 65536; i += 256) {
    u16 u = xr[i];
    if ((u & 0x7F80u) == 0x7F80u) c++;
  }
  atomicAdd(&cnt, c);
  __syncthreads();
  if (threadIdx.x == 0) flag[0] = (cnt >= 4) ? 1 : 0;  // 1 => inputs are f32
}

// ---- Wt[n][k] = W[k][n] so the MFMA B-operand reads contiguous k ----
__global__ void transpose_w(const u16* __restrict__ Wu, const float* __restrict__ Wf,
                            const int* __restrict__ flagp, u16* __restrict__ Wt) {
  int k = blockIdx.x;
  int n = threadIdx.x;
  if (flagp[0]) Wt[n * NF + k] = f2bf(Wf[k * NF + n]);
  else          Wt[n * NF + k] = Wu[k * NF + n];
}

__global__ void conv_bias(const u16* __restrict__ bu, const float* __restrict__ bf_,
                          const int* __restrict__ flagp, u16* __restrict__ o) {
  int i = threadIdx.x;
  if (flagp[0]) o[i] = f2bf(bf_[i]);
  else          o[i] = bu[i];
}

__global__ void copy_i32(const int* __restrict__ a, int* __restrict__ b, int n) {
  int i = blockIdx.x * 256 + threadIdx.x;
  if (i < n) b[i] = a[i];
}

// ---- counting-sort pipeline ----
__global__ void hist_kernel(const int* __restrict__ dst, int* __restrict__ counts) {
  int e = blockIdx.x * 256 + threadIdx.x;
  atomicAdd(&counts[dst[e]], 1);
}

__global__ void scanA(const int* __restrict__ counts, int* __restrict__ partial) {
  __shared__ int s[256];
  int t = threadIdx.x;
  int gid = blockIdx.x * 256 + t;
  int v = (gid < N_NODES) ? counts[gid] : 0;
  s[t] = v;
  __syncthreads();
  for (int offd = 128; offd > 0; offd >>= 1) {
    if (t < offd) s[t] += s[t + offd];
    __syncthreads();
  }
  if (t == 0) partial[blockIdx.x] = s[0];
}

__global__ void scanB(int* __restrict__ partial) {
  const int NPART = 391;
  __shared__ int s[512];
  int t = threadIdx.x;
  int v = (t < NPART) ? partial[t] : 0;
  s[t] = v;
  __syncthreads();
  for (int offd = 1; offd < 512; offd <<= 1) {
    int x = 0;
    if (t >= offd) x = s[t - offd];
    __syncthreads();
    s[t] += x;
    __syncthreads();
  }
  if (t < NPART) partial[t] = (t == 0) ? 0 : s[t - 1];  // exclusive
}

__global__ void scanC(const int* __restrict__ counts, const int* __restrict__ partial,
                      int* __restrict__ offs) {
  __shared__ int s[256];
  int t = threadIdx.x;
  int b = blockIdx.x;
  int gid = b * 256 + t;
  int v = (gid < N_NODES) ? counts[gid] : 0;
  s[t] = v;
  __syncthreads();
  for (int offd = 1; offd < 256; offd <<= 1) {
    int x = 0;
    if (t >= offd) x = s[t - offd];
    __syncthreads();
    s[t] += x;
    __syncthreads();
  }
  int incl = s[t];
  if (gid < N_NODES) offs[gid] = partial[b] + (incl - v);
  if (gid == N_NODES - 1) offs[N_NODES] = partial[b] + incl;
}

__global__ void scatter_full(const int* __restrict__ src, const int* __restrict__ dst,
                             const u16* __restrict__ wu, const float* __restrict__ wf,
                             const int* __restrict__ flagp, int* __restrict__ cursor,
                             int* __restrict__ ssrc, u16* __restrict__ sw) {
  int e = blockIdx.x * 256 + threadIdx.x;
  int d = dst[e];
  int pos = atomicAdd(&cursor[d], 1);
  ssrc[pos] = src[e];
  if (flagp[0]) sw[pos] = f2bf(wf[e]);
  else          sw[pos] = wu[e];
}

__global__ void scatter_eid(const int* __restrict__ dst, int* __restrict__ cursor,
                            int* __restrict__ seid) {
  int e = blockIdx.x * 256 + threadIdx.x;
  int d = dst[e];
  int pos = atomicAdd(&cursor[d], 1);
  seid[pos] = e;
}

// ---- bf16 MFMA GEMM: C[M,256] = A[M,256] @ W; A may be f32 (amask&&flag) ----
__global__ __launch_bounds__(256) void gemm_bf16(
    const u16* __restrict__ A2, const float* __restrict__ A4,
    const u16* __restrict__ Bt, u16* __restrict__ C, int M,
    const int* __restrict__ flagp, int amask) {
  __shared__ __align__(16) u16 Al[128][40];  // stride 80B: 2-way bank aliasing (free)
  __shared__ __align__(16) u16 Bl[128][40];
  const int afl = amask ? flagp[0] : 0;
  const int tid = threadIdx.x;
  const int m0 = blockIdx.x * 128;
  const int n0 = blockIdx.y * 128;
  const int lane = tid & 63;
  const int wave = tid >> 6;
  const int wm = (wave & 1) * 64;
  const int wn = (wave >> 1) * 64;
  const int mrow = lane & 15;
  const int grp = lane >> 4;

  f32x4_t acc[4][4];
  const f32x4_t zero = {0.f, 0.f, 0.f, 0.f};
#pragma unroll
  for (int i = 0; i < 4; ++i)
#pragma unroll
    for (int j = 0; j < 4; ++j) acc[i][j] = zero;

  for (int k0 = 0; k0 < NF; k0 += 32) {
#pragma unroll
    for (int r = 0; r < 2; ++r) {
      int chunk = tid + 256 * r;          // 0..511
      int row = chunk >> 2;               // 0..127
      int col = (chunk & 3) * 8;          // 0,8,16,24
      int gm = m0 + row;
      if (afl) {
        u16 t8[8];
        if (gm < M) {
          const float* p = A4 + (size_t)gm * NF + k0 + col;
          float4 ua = *(const float4*)(p);
          float4 ub = *(const float4*)(p + 4);
          t8[0] = f2bf(ua.x); t8[1] = f2bf(ua.y); t8[2] = f2bf(ua.z); t8[3] = f2bf(ua.w);
          t8[4] = f2bf(ub.x); t8[5] = f2bf(ub.y); t8[6] = f2bf(ub.z); t8[7] = f2bf(ub.w);
        } else {
          for (int q = 0; q < 8; ++q) t8[q] = 0;
        }
        *(uint4*)(&Al[row][col]) = *(const uint4*)t8;
      } else {
        uint4 va = make_uint4(0u, 0u, 0u, 0u);
        if (gm < M) va = *(const uint4*)(A2 + (size_t)gm * NF + k0 + col);
        *(uint4*)(&Al[row][col]) = va;
      }
      uint4 vb = *(const uint4*)(Bt + (size_t)(n0 + row) * NF + k0 + col);
      *(uint4*)(&Bl[row][col]) = vb;
    }
    __syncthreads();
    bf16x8_t af[4], bfr[4];
#pragma unroll
    for (int i = 0; i < 4; ++i)
      af[i] = *(const bf16x8_t*)(&Al[wm + i * 16 + mrow][grp * 8]);
#pragma unroll
    for (int j = 0; j < 4; ++j)
      bfr[j] = *(const bf16x8_t*)(&Bl[wn + j * 16 + mrow][grp * 8]);
#pragma unroll
    for (int i = 0; i < 4; ++i)
#pragma unroll
      for (int j = 0; j < 4; ++j)
        acc[i][j] = __builtin_amdgcn_mfma_f32_16x16x32_bf16(af[i], bfr[j], acc[i][j], 0, 0, 0);
    __syncthreads();
  }

  // C/D layout: col = lane&15, row = (lane>>4)*4 + r  [m89/m91 verified]
#pragma unroll
  for (int i = 0; i < 4; ++i) {
#pragma unroll
    for (int j = 0; j < 4; ++j) {
#pragma unroll
      for (int r = 0; r < 4; ++r) {
        int row = m0 + wm + i * 16 + grp * 4 + r;
        int col = n0 + wn + j * 16 + mrow;
        if (row < M) C[(size_t)row * NF + col] = f2bf(acc[i][j][r]);
      }
    }
  }
}

// ---- per-node aggregation + bias + ELU (full: sorted src+weight) ----
__global__ __launch_bounds__(256) void agg_full(
    const u16* __restrict__ sup, const int* __restrict__ offs,
    const int* __restrict__ ssrc, const u16* __restrict__ sw,
    const u16* __restrict__ bbf, u16* __restrict__ out2, float* __restrict__ out4,
    const int* __restrict__ flagp, int outmask) {
  int node = blockIdx.x * 4 + (threadIdx.x >> 6);
  int lane = threadIdx.x & 63;
  int c0 = lane * 4;
  float a0 = 0.f, a1 = 0.f, a2 = 0.f, a3 = 0.f;
  int e = offs[node];
  int eend = offs[node + 1];
  for (; e < eend; ++e) {
    int src = ssrc[e];
    float w = bf2f(sw[e]);
    ushort4 v = *(const ushort4*)(sup + (size_t)src * NF + c0);
    a0 += bf2f(v.x) * w;
    a1 += bf2f(v.y) * w;
    a2 += bf2f(v.z) * w;
    a3 += bf2f(v.w) * w;
  }
  ushort4 bv = *(const ushort4*)(bbf + c0);
  float r0 = a0 + bf2f(bv.x);
  float r1 = a1 + bf2f(bv.y);
  float r2 = a2 + bf2f(bv.z);
  float r3 = a3 + bf2f(bv.w);
  r0 = r0 > 0.f ? r0 : expm1f(r0);
  r1 = r1 > 0.f ? r1 : expm1f(r1);
  r2 = r2 > 0.f ? r2 : expm1f(r2);
  r3 = r3 > 0.f ? r3 : expm1f(r3);
  if (outmask && flagp[0]) {
    float4 o4;
    o4.x = r0; o4.y = r1; o4.z = r2; o4.w = r3;
    *(float4*)(out4 + (size_t)node * NF + c0) = o4;
  } else {
    ushort4 o;
    o.x = f2bf(r0); o.y = f2bf(r1); o.z = f2bf(r2); o.w = f2bf(r3);
    *(ushort4*)(out2 + (size_t)node * NF + c0) = o;
  }
}

// ---- compact variant: sorted edge-id, indirect to esrc/ew ----
__global__ __launch_bounds__(256) void agg_eid(
    const u16* __restrict__ sup, const int* __restrict__ offs,
    const int* __restrict__ seid, const int* __restrict__ esrc,
    const u16* __restrict__ ewu, const float* __restrict__ ewf,
    const u16* __restrict__ bbf, u16* __restrict__ out2, float* __restrict__ out4,
    const int* __restrict__ flagp, int outmask) {
  int node = blockIdx.x * 4 + (threadIdx.x >> 6);
  int lane = threadIdx.x & 63;
  int c0 = lane * 4;
  int isf = flagp[0];
  float a0 = 0.f, a1 = 0.f, a2 = 0.f, a3 = 0.f;
  int e = offs[node];
  int eend = offs[node + 1];
  for (; e < eend; ++e) {
    int eid = seid[e];
    int src = esrc[eid];
    float w = isf ? ewf[eid] : bf2f(ewu[eid]);
    ushort4 v = *(const ushort4*)(sup + (size_t)src * NF + c0);
    a0 += bf2f(v.x) * w;
    a1 += bf2f(v.y) * w;
    a2 += bf2f(v.z) * w;
    a3 += bf2f(v.w) * w;
  }
  ushort4 bv = *(const ushort4*)(bbf + c0);
  float r0 = a0 + bf2f(bv.x);
  float r1 = a1 + bf2f(bv.y);
  float r2 = a2 + bf2f(bv.z);
  float r3 = a3 + bf2f(bv.w);
  r0 = r0 > 0.f ? r0 : expm1f(r0);
  r1 = r1 > 0.f ? r1 : expm1f(r1);
  r2 = r2 > 0.f ? r2 : expm1f(r2);
  r3 = r3 > 0.f ? r3 : expm1f(r3);
  if (outmask && isf) {
    float4 o4;
    o4.x = r0; o4.y = r1; o4.z = r2; o4.w = r3;
    *(float4*)(out4 + (size_t)node * NF + c0) = o4;
  } else {
    ushort4 o;
    o.x = f2bf(r0); o.y = f2bf(r1); o.z = f2bf(r2); o.w = f2bf(r3);
    *(ushort4*)(out2 + (size_t)node * NF + c0) = o;
  }
}

extern "C" void kernel_launch(void* const* d_in, const int* in_sizes, int n_in,
                              void* d_out, int out_size, void* d_ws, size_t ws_size,
                              hipStream_t stream) {
  const u16* x2    = (const u16*)d_in[0];
  const float* x4  = (const float*)d_in[0];
  const u16* W1u   = (const u16*)d_in[1];
  const float* W1f = (const float*)d_in[1];
  const u16* b1u   = (const u16*)d_in[2];
  const float* b1f = (const float*)d_in[2];
  const u16* W2u   = (const u16*)d_in[3];
  const float* W2f = (const float*)d_in[3];
  const u16* b2u   = (const u16*)d_in[4];
  const float* b2f = (const float*)d_in[4];
  const u16* ewu   = (const u16*)d_in[5];
  const float* ewf = (const float*)d_in[5];
  const int* esrc  = (const int*)d_in[6];
  const int* edst  = (const int*)d_in[7];
  u16* out2  = (u16*)d_out;
  float* out4 = (float*)d_out;

  // explicit workspace layout (all offsets 256B-aligned)
  char* ws = (char*)d_ws;
  size_t oWt1     = 0;                      // 131072
  size_t oWt2     = 131072;                 // 131072
  size_t oSup     = 262144;                 // 51,200,000
  size_t oCounts  = 51462144;               // 400,384
  size_t oOffs    = 51862528;               // 400,384
  size_t oCursor  = 52262912;               // 400,384
  size_t oPartial = 52663296;               // 2048
  size_t oFlag    = 52665344;               // 256
  size_t oBb1     = 52665600;               // 1024
  size_t oBb2     = 52666624;               // 1024
  size_t oTail    = 52667648;
  size_t need_full = oTail + 12800000 + 6400000;  // ssrc + sw

  u16* Wt1     = (u16*)(ws + oWt1);
  u16* Wt2     = (u16*)(ws + oWt2);
  u16* sup     = (u16*)(ws + oSup);
  int* counts  = (int*)(ws + oCounts);
  int* offs    = (int*)(ws + oOffs);
  int* cursor  = (int*)(ws + oCursor);
  int* partial = (int*)(ws + oPartial);
  int* flag    = (int*)(ws + oFlag);
  u16* bb1     = (u16*)(ws + oBb1);
  u16* bb2     = (u16*)(ws + oBb2);

  u16* h1 = out2;  // d_out doubles as layer-1 activation (bf16, dead until final agg)

  sniff_kernel<<<1, 256, 0, stream>>>(x2, flag);
  hipMemsetAsync(counts, 0, (size_t)N_NODES * 4, stream);
  transpose_w<<<256, 256, 0, stream>>>(W1u, W1f, flag, Wt1);
  transpose_w<<<256, 256, 0, stream>>>(W2u, W2f, flag, Wt2);
  conv_bias<<<1, 256, 0, stream>>>(b1u, b1f, flag, bb1);
  conv_bias<<<1, 256, 0, stream>>>(b2u, b2f, flag, bb2);
  hist_kernel<<<N_EDGES / 256, 256, 0, stream>>>(edst, counts);
  scanA<<<391, 256, 0, stream>>>(counts, partial);
  scanB<<<1, 512, 0, stream>>>(partial);
  scanC<<<391, 256, 0, stream>>>(counts, partial, offs);
  copy_i32<<<391, 256, 0, stream>>>(offs, cursor, N_NODES);

  dim3 ggrid((N_NODES + 127) / 128, 2);

  if (ws_size >= need_full) {
    int* ssrc = (int*)(ws + oTail);
    u16* sw   = (u16*)(ws + oTail + 12800000);
    scatter_full<<<N_EDGES / 256, 256, 0, stream>>>(esrc, edst, ewu, ewf, flag, cursor, ssrc, sw);
    gemm_bf16<<<ggrid, 256, 0, stream>>>(x2, x4, Wt1, sup, N_NODES, flag, 1);
    agg_full<<<N_NODES / 4, 256, 0, stream>>>(sup, offs, ssrc, sw, bb1, h1, out4, flag, 0);
    gemm_bf16<<<ggrid, 256, 0, stream>>>(h1, (const float*)h1, Wt2, sup, N_NODES, flag, 0);
    agg_full<<<N_NODES / 4, 256, 0, stream>>>(sup, offs, ssrc, sw, bb2, out2, out4, flag, 1);
  } else {
    int* seid = (int*)(ws + oTail);
    scatter_eid<<<N_EDGES / 256, 256, 0, stream>>>(edst, cursor, seid);
    gemm_bf16<<<ggrid, 256, 0, stream>>>(x2, x4, Wt1, sup, N_NODES, flag, 1);
    agg_eid<<<N_NODES / 4, 256, 0, stream>>>(sup, offs, seid, esrc, ewu, ewf, bb1, h1, out4, flag, 0);
    gemm_bf16<<<ggrid, 256, 0, stream>>>(h1, (const float*)h1, Wt2, sup, N_NODES, flag, 0);
    agg_eid<<<N_NODES / 4, 256, 0, stream>>>(sup, offs, seid, esrc, ewu, ewf, bb2, out2, out4, flag, 1);
  }
}

// Round 5
// 1124.371 us; speedup vs baseline: 1.1733x; 1.1733x over previous
//
#include <hip/hip_runtime.h>
#include <math.h>

#define N_NODES 100000
#define N_EDGES 3200000
#define NF 256

typedef unsigned short u16;
typedef unsigned int u32;

typedef __bf16 bf16x8_t __attribute__((ext_vector_type(8)));
typedef float f32x4_t __attribute__((ext_vector_type(4)));

__device__ __forceinline__ float bf2f(u16 u) {
  union { u32 i; float f; } v; v.i = ((u32)u) << 16; return v.f;
}
__device__ __forceinline__ u16 f2bf(float f) {
  union { float f; u32 i; } v; v.f = f;
  u32 x = v.i;
  u32 r = (x + 0x7FFFu + ((x >> 16) & 1u)) >> 16;
  return (u16)r;
}

// ---- dtype sniff: bf16-NaN bit patterns appear in f32 mantissa halves only ----
__global__ void sniff_kernel(const u16* __restrict__ xr, int* __restrict__ flag) {
  __shared__ int cnt;
  if (threadIdx.x == 0) cnt = 0;
  __syncthreads();
  int c = 0;
  for (int i = threadIdx.x; i < 65536; i += 256) {
    u16 u = xr[i];
    if ((u & 0x7F80u) == 0x7F80u) c++;
  }
  atomicAdd(&cnt, c);
  __syncthreads();
  if (threadIdx.x == 0) flag[0] = (cnt >= 4) ? 1 : 0;  // 1 => inputs are f32
}

// ---- Wt[n][k] = W[k][n] so the MFMA B-operand reads contiguous k ----
__global__ void transpose_w(const u16* __restrict__ Wu, const float* __restrict__ Wf,
                            const int* __restrict__ flagp, u16* __restrict__ Wt) {
  int k = blockIdx.x;
  int n = threadIdx.x;
  if (flagp[0]) Wt[n * NF + k] = f2bf(Wf[k * NF + n]);
  else          Wt[n * NF + k] = Wu[k * NF + n];
}

__global__ void conv_bias(const u16* __restrict__ bu, const float* __restrict__ bf_,
                          const int* __restrict__ flagp, u16* __restrict__ o) {
  int i = threadIdx.x;
  if (flagp[0]) o[i] = f2bf(bf_[i]);
  else          o[i] = bu[i];
}

__global__ void copy_i32(const int* __restrict__ a, int* __restrict__ b, int n) {
  int i = blockIdx.x * 256 + threadIdx.x;
  if (i < n) b[i] = a[i];
}

// ---- counting-sort pipeline ----
__global__ void hist_kernel(const int* __restrict__ dst, int* __restrict__ counts) {
  int e = blockIdx.x * 256 + threadIdx.x;
  atomicAdd(&counts[dst[e]], 1);
}

__global__ void scanA(const int* __restrict__ counts, int* __restrict__ partial) {
  __shared__ int s[256];
  int t = threadIdx.x;
  int gid = blockIdx.x * 256 + t;
  int v = (gid < N_NODES) ? counts[gid] : 0;
  s[t] = v;
  __syncthreads();
  for (int offd = 128; offd > 0; offd >>= 1) {
    if (t < offd) s[t] += s[t + offd];
    __syncthreads();
  }
  if (t == 0) partial[blockIdx.x] = s[0];
}

__global__ void scanB(int* __restrict__ partial) {
  const int NPART = 391;
  __shared__ int s[512];
  int t = threadIdx.x;
  int v = (t < NPART) ? partial[t] : 0;
  s[t] = v;
  __syncthreads();
  for (int offd = 1; offd < 512; offd <<= 1) {
    int x = 0;
    if (t >= offd) x = s[t - offd];
    __syncthreads();
    s[t] += x;
    __syncthreads();
  }
  if (t < NPART) partial[t] = (t == 0) ? 0 : s[t - 1];  // exclusive
}

__global__ void scanC(const int* __restrict__ counts, const int* __restrict__ partial,
                      int* __restrict__ offs) {
  __shared__ int s[256];
  int t = threadIdx.x;
  int b = blockIdx.x;
  int gid = b * 256 + t;
  int v = (gid < N_NODES) ? counts[gid] : 0;
  s[t] = v;
  __syncthreads();
  for (int offd = 1; offd < 256; offd <<= 1) {
    int x = 0;
    if (t >= offd) x = s[t - offd];
    __syncthreads();
    s[t] += x;
    __syncthreads();
  }
  int incl = s[t];
  if (gid < N_NODES) offs[gid] = partial[b] + (incl - v);
  if (gid == N_NODES - 1) offs[N_NODES] = partial[b] + incl;
}

__global__ void scatter_full(const int* __restrict__ src, const int* __restrict__ dst,
                             const u16* __restrict__ wu, const float* __restrict__ wf,
                             const int* __restrict__ flagp, int* __restrict__ cursor,
                             int* __restrict__ ssrc, u16* __restrict__ sw) {
  int e = blockIdx.x * 256 + threadIdx.x;
  int d = dst[e];
  int pos = atomicAdd(&cursor[d], 1);
  ssrc[pos] = src[e];
  if (flagp[0]) sw[pos] = f2bf(wf[e]);
  else          sw[pos] = wu[e];
}

__global__ void scatter_eid(const int* __restrict__ dst, int* __restrict__ cursor,
                            int* __restrict__ seid) {
  int e = blockIdx.x * 256 + threadIdx.x;
  int d = dst[e];
  int pos = atomicAdd(&cursor[d], 1);
  seid[pos] = e;
}

// ---- bf16 MFMA GEMM: C[M,256] = A[M,256] @ W; A may be f32 (amask&&flag) ----
__global__ __launch_bounds__(256) void gemm_bf16(
    const u16* __restrict__ A2, const float* __restrict__ A4,
    const u16* __restrict__ Bt, u16* __restrict__ C, int M,
    const int* __restrict__ flagp, int amask) {
  __shared__ __align__(16) u16 Al[128][40];  // stride 80B: 2-way bank aliasing (free)
  __shared__ __align__(16) u16 Bl[128][40];
  const int afl = amask ? flagp[0] : 0;
  const int tid = threadIdx.x;
  const int m0 = blockIdx.x * 128;
  const int n0 = blockIdx.y * 128;
  const int lane = tid & 63;
  const int wave = tid >> 6;
  const int wm = (wave & 1) * 64;
  const int wn = (wave >> 1) * 64;
  const int mrow = lane & 15;
  const int grp = lane >> 4;

  f32x4_t acc[4][4];
  const f32x4_t zero = {0.f, 0.f, 0.f, 0.f};
#pragma unroll
  for (int i = 0; i < 4; ++i)
#pragma unroll
    for (int j = 0; j < 4; ++j) acc[i][j] = zero;

  for (int k0 = 0; k0 < NF; k0 += 32) {
#pragma unroll
    for (int r = 0; r < 2; ++r) {
      int chunk = tid + 256 * r;          // 0..511
      int row = chunk >> 2;               // 0..127
      int col = (chunk & 3) * 8;          // 0,8,16,24
      int gm = m0 + row;
      if (afl) {
        u16 t8[8];
        if (gm < M) {
          const float* p = A4 + (size_t)gm * NF + k0 + col;
          float4 ua = *(const float4*)(p);
          float4 ub = *(const float4*)(p + 4);
          t8[0] = f2bf(ua.x); t8[1] = f2bf(ua.y); t8[2] = f2bf(ua.z); t8[3] = f2bf(ua.w);
          t8[4] = f2bf(ub.x); t8[5] = f2bf(ub.y); t8[6] = f2bf(ub.z); t8[7] = f2bf(ub.w);
        } else {
          for (int q = 0; q < 8; ++q) t8[q] = 0;
        }
        *(uint4*)(&Al[row][col]) = *(const uint4*)t8;
      } else {
        uint4 va = make_uint4(0u, 0u, 0u, 0u);
        if (gm < M) va = *(const uint4*)(A2 + (size_t)gm * NF + k0 + col);
        *(uint4*)(&Al[row][col]) = va;
      }
      uint4 vb = *(const uint4*)(Bt + (size_t)(n0 + row) * NF + k0 + col);
      *(uint4*)(&Bl[row][col]) = vb;
    }
    __syncthreads();
    bf16x8_t af[4], bfr[4];
#pragma unroll
    for (int i = 0; i < 4; ++i)
      af[i] = *(const bf16x8_t*)(&Al[wm + i * 16 + mrow][grp * 8]);
#pragma unroll
    for (int j = 0; j < 4; ++j)
      bfr[j] = *(const bf16x8_t*)(&Bl[wn + j * 16 + mrow][grp * 8]);
#pragma unroll
    for (int i = 0; i < 4; ++i)
#pragma unroll
      for (int j = 0; j < 4; ++j)
        acc[i][j] = __builtin_amdgcn_mfma_f32_16x16x32_bf16(af[i], bfr[j], acc[i][j], 0, 0, 0);
    __syncthreads();
  }

  // C/D layout: col = lane&15, row = (lane>>4)*4 + r  [m89/m91 verified]
#pragma unroll
  for (int i = 0; i < 4; ++i) {
#pragma unroll
    for (int j = 0; j < 4; ++j) {
#pragma unroll
      for (int r = 0; r < 4; ++r) {
        int row = m0 + wm + i * 16 + grp * 4 + r;
        int col = n0 + wn + j * 16 + mrow;
        if (row < M) C[(size_t)row * NF + col] = f2bf(acc[i][j][r]);
      }
    }
  }
}

// ---- per-node aggregation + bias + ELU (full: sorted src+weight), 8x MLP unroll ----
__global__ __launch_bounds__(256) void agg_full(
    const u16* __restrict__ sup, const int* __restrict__ offs,
    const int* __restrict__ ssrc, const u16* __restrict__ sw,
    const u16* __restrict__ bbf, u16* __restrict__ out2, float* __restrict__ out4,
    const int* __restrict__ flagp, int outmask) {
  int node = blockIdx.x * 4 + (threadIdx.x >> 6);
  int lane = threadIdx.x & 63;
  int c0 = lane * 4;
  float a0 = 0.f, a1 = 0.f, a2 = 0.f, a3 = 0.f;
  int e = offs[node];
  int eend = offs[node + 1];

  for (; e + 8 <= eend; e += 8) {
    int s0 = ssrc[e + 0], s1 = ssrc[e + 1], s2 = ssrc[e + 2], s3 = ssrc[e + 3];
    int s4 = ssrc[e + 4], s5 = ssrc[e + 5], s6 = ssrc[e + 6], s7 = ssrc[e + 7];
    float w0 = bf2f(sw[e + 0]), w1 = bf2f(sw[e + 1]), w2 = bf2f(sw[e + 2]), w3 = bf2f(sw[e + 3]);
    float w4 = bf2f(sw[e + 4]), w5 = bf2f(sw[e + 5]), w6 = bf2f(sw[e + 6]), w7 = bf2f(sw[e + 7]);
    ushort4 v0 = *(const ushort4*)(sup + (size_t)s0 * NF + c0);
    ushort4 v1 = *(const ushort4*)(sup + (size_t)s1 * NF + c0);
    ushort4 v2 = *(const ushort4*)(sup + (size_t)s2 * NF + c0);
    ushort4 v3 = *(const ushort4*)(sup + (size_t)s3 * NF + c0);
    ushort4 v4 = *(const ushort4*)(sup + (size_t)s4 * NF + c0);
    ushort4 v5 = *(const ushort4*)(sup + (size_t)s5 * NF + c0);
    ushort4 v6 = *(const ushort4*)(sup + (size_t)s6 * NF + c0);
    ushort4 v7 = *(const ushort4*)(sup + (size_t)s7 * NF + c0);
    a0 += bf2f(v0.x) * w0; a1 += bf2f(v0.y) * w0; a2 += bf2f(v0.z) * w0; a3 += bf2f(v0.w) * w0;
    a0 += bf2f(v1.x) * w1; a1 += bf2f(v1.y) * w1; a2 += bf2f(v1.z) * w1; a3 += bf2f(v1.w) * w1;
    a0 += bf2f(v2.x) * w2; a1 += bf2f(v2.y) * w2; a2 += bf2f(v2.z) * w2; a3 += bf2f(v2.w) * w2;
    a0 += bf2f(v3.x) * w3; a1 += bf2f(v3.y) * w3; a2 += bf2f(v3.z) * w3; a3 += bf2f(v3.w) * w3;
    a0 += bf2f(v4.x) * w4; a1 += bf2f(v4.y) * w4; a2 += bf2f(v4.z) * w4; a3 += bf2f(v4.w) * w4;
    a0 += bf2f(v5.x) * w5; a1 += bf2f(v5.y) * w5; a2 += bf2f(v5.z) * w5; a3 += bf2f(v5.w) * w5;
    a0 += bf2f(v6.x) * w6; a1 += bf2f(v6.y) * w6; a2 += bf2f(v6.z) * w6; a3 += bf2f(v6.w) * w6;
    a0 += bf2f(v7.x) * w7; a1 += bf2f(v7.y) * w7; a2 += bf2f(v7.z) * w7; a3 += bf2f(v7.w) * w7;
  }
  for (; e < eend; ++e) {
    int src = ssrc[e];
    float w = bf2f(sw[e]);
    ushort4 v = *(const ushort4*)(sup + (size_t)src * NF + c0);
    a0 += bf2f(v.x) * w;
    a1 += bf2f(v.y) * w;
    a2 += bf2f(v.z) * w;
    a3 += bf2f(v.w) * w;
  }
  ushort4 bv = *(const ushort4*)(bbf + c0);
  float r0 = a0 + bf2f(bv.x);
  float r1 = a1 + bf2f(bv.y);
  float r2 = a2 + bf2f(bv.z);
  float r3 = a3 + bf2f(bv.w);
  r0 = r0 > 0.f ? r0 : expm1f(r0);
  r1 = r1 > 0.f ? r1 : expm1f(r1);
  r2 = r2 > 0.f ? r2 : expm1f(r2);
  r3 = r3 > 0.f ? r3 : expm1f(r3);
  if (outmask && flagp[0]) {
    float4 o4;
    o4.x = r0; o4.y = r1; o4.z = r2; o4.w = r3;
    *(float4*)(out4 + (size_t)node * NF + c0) = o4;
  } else {
    ushort4 o;
    o.x = f2bf(r0); o.y = f2bf(r1); o.z = f2bf(r2); o.w = f2bf(r3);
    *(ushort4*)(out2 + (size_t)node * NF + c0) = o;
  }
}

// ---- compact variant: sorted edge-id, indirect to esrc/ew ----
__global__ __launch_bounds__(256) void agg_eid(
    const u16* __restrict__ sup, const int* __restrict__ offs,
    const int* __restrict__ seid, const int* __restrict__ esrc,
    const u16* __restrict__ ewu, const float* __restrict__ ewf,
    const u16* __restrict__ bbf, u16* __restrict__ out2, float* __restrict__ out4,
    const int* __restrict__ flagp, int outmask) {
  int node = blockIdx.x * 4 + (threadIdx.x >> 6);
  int lane = threadIdx.x & 63;
  int c0 = lane * 4;
  int isf = flagp[0];
  float a0 = 0.f, a1 = 0.f, a2 = 0.f, a3 = 0.f;
  int e = offs[node];
  int eend = offs[node + 1];
  for (; e < eend; ++e) {
    int eid = seid[e];
    int src = esrc[eid];
    float w = isf ? ewf[eid] : bf2f(ewu[eid]);
    ushort4 v = *(const ushort4*)(sup + (size_t)src * NF + c0);
    a0 += bf2f(v.x) * w;
    a1 += bf2f(v.y) * w;
    a2 += bf2f(v.z) * w;
    a3 += bf2f(v.w) * w;
  }
  ushort4 bv = *(const ushort4*)(bbf + c0);
  float r0 = a0 + bf2f(bv.x);
  float r1 = a1 + bf2f(bv.y);
  float r2 = a2 + bf2f(bv.z);
  float r3 = a3 + bf2f(bv.w);
  r0 = r0 > 0.f ? r0 : expm1f(r0);
  r1 = r1 > 0.f ? r1 : expm1f(r1);
  r2 = r2 > 0.f ? r2 : expm1f(r2);
  r3 = r3 > 0.f ? r3 : expm1f(r3);
  if (outmask && isf) {
    float4 o4;
    o4.x = r0; o4.y = r1; o4.z = r2; o4.w = r3;
    *(float4*)(out4 + (size_t)node * NF + c0) = o4;
  } else {
    ushort4 o;
    o.x = f2bf(r0); o.y = f2bf(r1); o.z = f2bf(r2); o.w = f2bf(r3);
    *(ushort4*)(out2 + (size_t)node * NF + c0) = o;
  }
}

extern "C" void kernel_launch(void* const* d_in, const int* in_sizes, int n_in,
                              void* d_out, int out_size, void* d_ws, size_t ws_size,
                              hipStream_t stream) {
  const u16* x2    = (const u16*)d_in[0];
  const float* x4  = (const float*)d_in[0];
  const u16* W1u   = (const u16*)d_in[1];
  const float* W1f = (const float*)d_in[1];
  const u16* b1u   = (const u16*)d_in[2];
  const float* b1f = (const float*)d_in[2];
  const u16* W2u   = (const u16*)d_in[3];
  const float* W2f = (const float*)d_in[3];
  const u16* b2u   = (const u16*)d_in[4];
  const float* b2f = (const float*)d_in[4];
  const u16* ewu   = (const u16*)d_in[5];
  const float* ewf = (const float*)d_in[5];
  const int* esrc  = (const int*)d_in[6];
  const int* edst  = (const int*)d_in[7];
  u16* out2  = (u16*)d_out;
  float* out4 = (float*)d_out;

  // explicit workspace layout (all offsets 256B-aligned)
  char* ws = (char*)d_ws;
  size_t oWt1     = 0;                      // 131072
  size_t oWt2     = 131072;                 // 131072
  size_t oSup     = 262144;                 // 51,200,000
  size_t oCounts  = 51462144;               // 400,384
  size_t oOffs    = 51862528;               // 400,384
  size_t oCursor  = 52262912;               // 400,384
  size_t oPartial = 52663296;               // 2048
  size_t oFlag    = 52665344;               // 256
  size_t oBb1     = 52665600;               // 1024
  size_t oBb2     = 52666624;               // 1024
  size_t oTail    = 52667648;
  size_t need_full = oTail + 12800000 + 6400000;  // ssrc + sw

  u16* Wt1     = (u16*)(ws + oWt1);
  u16* Wt2     = (u16*)(ws + oWt2);
  u16* sup     = (u16*)(ws + oSup);
  int* counts  = (int*)(ws + oCounts);
  int* offs    = (int*)(ws + oOffs);
  int* cursor  = (int*)(ws + oCursor);
  int* partial = (int*)(ws + oPartial);
  int* flag    = (int*)(ws + oFlag);
  u16* bb1     = (u16*)(ws + oBb1);
  u16* bb2     = (u16*)(ws + oBb2);

  u16* h1 = out2;  // d_out doubles as layer-1 activation (bf16, dead until final agg)

  sniff_kernel<<<1, 256, 0, stream>>>(x2, flag);
  hipMemsetAsync(counts, 0, (size_t)N_NODES * 4, stream);
  transpose_w<<<256, 256, 0, stream>>>(W1u, W1f, flag, Wt1);
  transpose_w<<<256, 256, 0, stream>>>(W2u, W2f, flag, Wt2);
  conv_bias<<<1, 256, 0, stream>>>(b1u, b1f, flag, bb1);
  conv_bias<<<1, 256, 0, stream>>>(b2u, b2f, flag, bb2);
  hist_kernel<<<N_EDGES / 256, 256, 0, stream>>>(edst, counts);
  scanA<<<391, 256, 0, stream>>>(counts, partial);
  scanB<<<1, 512, 0, stream>>>(partial);
  scanC<<<391, 256, 0, stream>>>(counts, partial, offs);
  copy_i32<<<391, 256, 0, stream>>>(offs, cursor, N_NODES);

  dim3 ggrid((N_NODES + 127) / 128, 2);

  if (ws_size >= need_full) {
    int* ssrc = (int*)(ws + oTail);
    u16* sw   = (u16*)(ws + oTail + 12800000);
    scatter_full<<<N_EDGES / 256, 256, 0, stream>>>(esrc, edst, ewu, ewf, flag, cursor, ssrc, sw);
    gemm_bf16<<<ggrid, 256, 0, stream>>>(x2, x4, Wt1, sup, N_NODES, flag, 1);
    agg_full<<<N_NODES / 4, 256, 0, stream>>>(sup, offs, ssrc, sw, bb1, h1, out4, flag, 0);
    gemm_bf16<<<ggrid, 256, 0, stream>>>(h1, (const float*)h1, Wt2, sup, N_NODES, flag, 0);
    agg_full<<<N_NODES / 4, 256, 0, stream>>>(sup, offs, ssrc, sw, bb2, out2, out4, flag, 1);
  } else {
    int* seid = (int*)(ws + oTail);
    scatter_eid<<<N_EDGES / 256, 256, 0, stream>>>(edst, cursor, seid);
    gemm_bf16<<<ggrid, 256, 0, stream>>>(x2, x4, Wt1, sup, N_NODES, flag, 1);
    agg_eid<<<N_NODES / 4, 256, 0, stream>>>(sup, offs, seid, esrc, ewu, ewf, bb1, h1, out4, flag, 0);
    gemm_bf16<<<ggrid, 256, 0, stream>>>(h1, (const float*)h1, Wt2, sup, N_NODES, flag, 0);
    agg_eid<<<N_NODES / 4, 256, 0, stream>>>(sup, offs, seid, esrc, ewu, ewf, bb2, out2, out4, flag, 1);
  }
}